// Round 10
// baseline (60.658 us; speedup 1.0000x reference)
//
#include <hip/hip_runtime.h>

#define M_DIM 64
#define K_DIM 8192
#define N_DIM 8192
#define QB 32
#define NT 64               // N columns per block
#define KC 64               // K per stage (2 quant blocks)
#define SPLITS 4
#define KSPLIT (K_DIM / SPLITS)    // 2048
#define NSTAGE (KSPLIT / KC)       // 32 (divisible by 4: 4-set rotation)

typedef __attribute__((ext_vector_type(8))) short short8;     // MFMA A/B frag
typedef __attribute__((ext_vector_type(8))) unsigned short ushort8;
typedef __attribute__((ext_vector_type(4))) float f32x4;
typedef __attribute__((ext_vector_type(4))) unsigned int u32x4;

static_assert(NSTAGE % 4 == 0 && NSTAGE * KC == KSPLIT, "tiling");

// f32 -> bf16 round-to-nearest-even
__device__ __forceinline__ unsigned short f2bf(float f) {
    unsigned u = __builtin_bit_cast(unsigned, f);
    u += 0x7fffu + ((u >> 16) & 1u);
    return (unsigned short)(u >> 16);
}

// Rewrites the whole output with bias every call (clears the 0xAA poison;
// qgemm atomicAdds on top of this).
__global__ __launch_bounds__(256) void bias_init(const float* __restrict__ bias,
                                                 float* __restrict__ out) {
    int i = (blockIdx.x * 256 + threadIdx.x) * 4;
    *(f32x4*)(out + i) = *(const f32x4*)(bias + (i & (N_DIM - 1)));
}

// One-shot x f32 -> bf16 into workspace (1 MB, L2-resident).
__global__ __launch_bounds__(256) void xcvt(const float* __restrict__ x,
                                            unsigned short* __restrict__ xb) {
    int i = (blockIdx.x * 256 + threadIdx.x) * 8;
    f32x4 a = *(const f32x4*)(x + i);
    f32x4 b = *(const f32x4*)(x + i + 4);
    ushort8 o;
    #pragma unroll
    for (int e = 0; e < 4; ++e) { o[e] = f2bf(a[e]); o[4 + e] = f2bf(b[e]); }
    *(ushort8*)(xb + i) = o;
}

// R9 structure + the paired lever neither R8 nor R9 had alone:
//  * 2-stage-deep prefetch over 4 rotating register sets (issue at stage
//    top; consumed 2 stages = ~6k cy later, >> ~900 cy HBM latency).
//  * lgkmcnt(0)-only barrier (raw s_barrier): prefetch vmem stays in
//    flight across 2 barrier crossings; no vmcnt(0) drain anywhere in the
//    loop; the compiler's counted vmcnt at each dequant is trivially
//    satisfied.
// Double-buffer safety with one barrier/stage: buffer b is rewritten at
// stage t+2, which in program order is after barrier(t+1); all reads of b
// at stage t complete before the reader reaches barrier(t+1). Same-wave
// LDS visibility at the barrier is the explicit lgkmcnt(0).
template <bool XBF>
__global__ __launch_bounds__(256, 2) void qgemm(
    const float* __restrict__ x,             // [M][K] f32 (fallback)
    const unsigned short* __restrict__ xb,   // [M][K] bf16 (main)
    const float* __restrict__ scales,        // [K/QB][N]
    const float* __restrict__ zeros,         // [K/QB][N]
    const int*   __restrict__ qw,            // [K][N], 0..255
    float*       __restrict__ out)           // [M][N]
{
    __shared__ unsigned short lq[2][NT][72];   // [n][k] bf16, 144B rows
    __shared__ unsigned short lx[2][M_DIM][72];

    const int tid  = threadIdx.x;
    const int lane = tid & 63;
    const int w    = tid >> 6;          // wave 0..3, owns cols [16w,16w+16)

    const int n0 = blockIdx.x * NT;
    const int k0 = blockIdx.y * KSPLIT;

    const int qn   = n0 + lane;         // this thread's weight column
    const int xrow = tid >> 2;          // x staging: row 0..63
    const int xcol = (tid & 3) * 16;    // 16 k's per thread

    const int*   qp = qw     + (size_t)k0 * N_DIM + qn;
    const float* sp = scales + (size_t)(k0 >> 5) * N_DIM + qn;
    const float* zp = zeros  + (size_t)(k0 >> 5) * N_DIM + qn;

    // 4 rotating stage-register sets (all statically indexed)
    int qv0[16], qv1[16], qv2[16], qv3[16];
    float s0_0, s1_0, z0_0, z1_0, s0_1, s1_1, z0_1, z1_1;
    float s0_2, s1_2, z0_2, z1_2, s0_3, s1_3, z0_3, z1_3;
    u32x4 xv0[2], xv1[2], xv2[2], xv3[2];
    f32x4 xf0[4], xf1[4], xf2[4], xf3[4];

#define LOADS(S, T)                                                           \
    do {                                                                      \
        const int* _p = qp + (size_t)(T) * KC * N_DIM;                        \
        _Pragma("unroll")                                                     \
        for (int s = 0; s < 4; ++s)                                           \
            _Pragma("unroll")                                                 \
            for (int j = 0; j < 4; ++j)                                       \
                qv##S[4 * s + j] = _p[(size_t)(16 * s + 4 * w + j) * N_DIM];  \
        s0_##S = sp[(size_t)(2 * (T)) * N_DIM];                               \
        s1_##S = sp[(size_t)(2 * (T) + 1) * N_DIM];                           \
        z0_##S = zp[(size_t)(2 * (T)) * N_DIM];                               \
        z1_##S = zp[(size_t)(2 * (T) + 1) * N_DIM];                           \
        if (XBF) {                                                            \
            const unsigned short* _xp =                                       \
                xb + (size_t)xrow * K_DIM + (k0 + (T) * KC) + xcol;           \
            xv##S[0] = *(const u32x4*)_xp;                                    \
            xv##S[1] = *(const u32x4*)(_xp + 8);                              \
        } else {                                                              \
            const float* _xp =                                                \
                x + (size_t)xrow * K_DIM + (k0 + (T) * KC) + xcol;            \
            _Pragma("unroll")                                                 \
            for (int i = 0; i < 4; ++i) xf##S[i] = *(const f32x4*)(_xp + 4 * i); \
        }                                                                     \
    } while (0)

#define BODY(S, CUR)                                                          \
    do {                                                                      \
        const float _nz0 = -s0_##S * z0_##S, _nz1 = -s1_##S * z1_##S;         \
        uint2 qd[4];                                                          \
        _Pragma("unroll")                                                     \
        for (int s = 0; s < 4; ++s) {                                         \
            const float _sc = (s < 2) ? s0_##S : s1_##S;                      \
            const float _nz = (s < 2) ? _nz0 : _nz1;                          \
            unsigned short h0 = f2bf(fmaf((float)qv##S[4 * s + 0], _sc, _nz)); \
            unsigned short h1 = f2bf(fmaf((float)qv##S[4 * s + 1], _sc, _nz)); \
            unsigned short h2 = f2bf(fmaf((float)qv##S[4 * s + 2], _sc, _nz)); \
            unsigned short h3 = f2bf(fmaf((float)qv##S[4 * s + 3], _sc, _nz)); \
            qd[s].x = (unsigned)h0 | ((unsigned)h1 << 16);                    \
            qd[s].y = (unsigned)h2 | ((unsigned)h3 << 16);                    \
        }                                                                     \
        _Pragma("unroll")                                                     \
        for (int s = 0; s < 4; ++s)                                           \
            *(uint2*)&lq[CUR][lane][16 * s + 4 * w] = qd[s];                  \
        if (XBF) {                                                            \
            *(u32x4*)&lx[CUR][xrow][xcol]     = xv##S[0];                     \
            *(u32x4*)&lx[CUR][xrow][xcol + 8] = xv##S[1];                     \
        } else {                                                              \
            ushort8 xw0, xw1;                                                 \
            _Pragma("unroll")                                                 \
            for (int e = 0; e < 4; ++e) {                                     \
                xw0[e]     = f2bf(xf##S[0][e]);                               \
                xw0[4 + e] = f2bf(xf##S[1][e]);                               \
                xw1[e]     = f2bf(xf##S[2][e]);                               \
                xw1[4 + e] = f2bf(xf##S[3][e]);                               \
            }                                                                 \
            *(ushort8*)&lx[CUR][xrow][xcol]     = xw0;                        \
            *(ushort8*)&lx[CUR][xrow][xcol + 8] = xw1;                        \
        }                                                                     \
    } while (0)

#define MM(CUR)                                                               \
    do {                                                                      \
        _Pragma("unroll")                                                     \
        for (int c = 0; c < 2; ++c) {                                         \
            const short8 bf = *(const short8*)&lq[CUR][16 * w + (lane & 15)]  \
                                                 [32 * c + 8 * (lane >> 4)];  \
            _Pragma("unroll")                                                 \
            for (int r = 0; r < 4; ++r) {                                     \
                const short8 af = *(const short8*)&lx[CUR][16 * r + (lane & 15)] \
                                                     [32 * c + 8 * (lane >> 4)]; \
                acc[r] = __builtin_amdgcn_mfma_f32_16x16x32_bf16(af, bf, acc[r], 0, 0, 0); \
            }                                                                 \
        }                                                                     \
    } while (0)

// One pipeline stage: issue loads 2 ahead (set P), dequant+stage set S,
// raw barrier (no vmcnt drain), MFMA.
#define STAGE(S, P, T, CUR)                                                   \
    do {                                                                      \
        if ((T) + 2 < NSTAGE) LOADS(P, (T) + 2);                              \
        BODY(S, CUR);                                                         \
        asm volatile("s_waitcnt lgkmcnt(0)" ::: "memory");                    \
        __builtin_amdgcn_s_barrier();                                         \
        MM(CUR);                                                              \
    } while (0)

    f32x4 acc[4];
    #pragma unroll
    for (int r = 0; r < 4; ++r) acc[r] = (f32x4){0.f, 0.f, 0.f, 0.f};

    // prologue: stages 0 and 1 in flight
    LOADS(0, 0);
    LOADS(1, 1);

    for (int t = 0; t < NSTAGE; t += 4) {
        STAGE(0, 2, t + 0, 0);
        STAGE(1, 3, t + 1, 1);
        STAGE(2, 0, t + 2, 0);
        STAGE(3, 1, t + 3, 1);
    }

#undef LOADS
#undef BODY
#undef MM
#undef STAGE

    // epilogue: C layout col=lane&15, row=4*(lane>>4)+e (validated)
    const int cn = n0 + 16 * w + (lane & 15);
    #pragma unroll
    for (int r = 0; r < 4; ++r) {
        const int m = 16 * r + 4 * (lane >> 4);
        #pragma unroll
        for (int e = 0; e < 4; ++e)
            atomicAdd(out + (size_t)(m + e) * N_DIM + cn, acc[r][e]);
    }
}

extern "C" void kernel_launch(void* const* d_in, const int* in_sizes, int n_in,
                              void* d_out, int out_size, void* d_ws, size_t ws_size,
                              hipStream_t stream) {
    const float* x      = (const float*)d_in[0];
    const float* scales = (const float*)d_in[1];
    const float* zeros  = (const float*)d_in[2];
    const float* bias   = (const float*)d_in[3];
    const int*   qw     = (const int*)d_in[4];
    float* out = (float*)d_out;
    unsigned short* xbf = (unsigned short*)d_ws;

    const bool use_xbf = ws_size >= (size_t)M_DIM * K_DIM * 2;

    bias_init<<<dim3((M_DIM * N_DIM) / 1024), 256, 0, stream>>>(bias, out);
    if (use_xbf) {
        xcvt<<<dim3((M_DIM * K_DIM) / 2048), 256, 0, stream>>>(x, xbf);
        qgemm<true><<<dim3(N_DIM / NT, SPLITS), 256, 0, stream>>>(
            x, xbf, scales, zeros, qw, out);
    } else {
        qgemm<false><<<dim3(N_DIM / NT, SPLITS), 256, 0, stream>>>(
            x, nullptr, scales, zeros, qw, out);
    }
}